// Round 1
// baseline (1480.556 us; speedup 1.0000x reference)
//
#include <hip/hip_runtime.h>
#include <math.h>

// Problem constants
#define NH     8
#define DK     64
#define DV     64
#define LQ     100
#define LK     100
#define BS     32
#define DM     512
#define TEMP   20.0f

// ---------------------------------------------------------------------------
// Projection GEMM: C[M,N] = A[M,K] @ B[N,K]^T   (M=3200, N=512, K=512)
// 64x64 tile, 256 threads, 4x4 micro-tile per thread, K-tile 16.
// ---------------------------------------------------------------------------
__global__ __launch_bounds__(256) void proj_gemm(const float* __restrict__ A,
                                                 const float* __restrict__ B,
                                                 float* __restrict__ C) {
    __shared__ float As[64 * 17];
    __shared__ float Bs[64 * 17];

    const int t  = threadIdx.x;
    const int tx = t & 15, ty = t >> 4;
    const int bm = blockIdx.x * 64, bn = blockIdx.y * 64;

    const int lr = t >> 2;          // 0..63 load row
    const int lc = (t & 3) * 4;     // 0,4,8,12 load col (k)

    float acc[4][4];
#pragma unroll
    for (int i = 0; i < 4; ++i)
#pragma unroll
        for (int j = 0; j < 4; ++j) acc[i][j] = 0.f;

    for (int k0 = 0; k0 < DM; k0 += 16) {
        float4 av = *(const float4*)&A[(size_t)(bm + lr) * DM + k0 + lc];
        float4 bv = *(const float4*)&B[(size_t)(bn + lr) * DM + k0 + lc];
        __syncthreads();
        As[lr * 17 + lc + 0] = av.x; As[lr * 17 + lc + 1] = av.y;
        As[lr * 17 + lc + 2] = av.z; As[lr * 17 + lc + 3] = av.w;
        Bs[lr * 17 + lc + 0] = bv.x; Bs[lr * 17 + lc + 1] = bv.y;
        Bs[lr * 17 + lc + 2] = bv.z; Bs[lr * 17 + lc + 3] = bv.w;
        __syncthreads();
#pragma unroll
        for (int kk = 0; kk < 16; ++kk) {
            float a[4], b[4];
#pragma unroll
            for (int i = 0; i < 4; ++i) a[i] = As[(ty * 4 + i) * 17 + kk];
#pragma unroll
            for (int j = 0; j < 4; ++j) b[j] = Bs[(tx * 4 + j) * 17 + kk];
#pragma unroll
            for (int i = 0; i < 4; ++i)
#pragma unroll
                for (int j = 0; j < 4; ++j) acc[i][j] += a[i] * b[j];
        }
    }
#pragma unroll
    for (int i = 0; i < 4; ++i) {
        float4 o = make_float4(acc[i][0], acc[i][1], acc[i][2], acc[i][3]);
        *(float4*)&C[(size_t)(bm + ty * 4 + i) * 512 + bn + tx * 4] = o;
    }
}

// ---------------------------------------------------------------------------
// In-place L2 normalization of contiguous 64-float chunks. One wave per chunk.
// 25600 chunks in Pq, 25600 in Pk -> 51200 waves -> 12800 blocks of 256.
// ---------------------------------------------------------------------------
__global__ __launch_bounds__(256) void l2norm_chunks(float* __restrict__ Pq,
                                                     float* __restrict__ Pk) {
    int wid  = blockIdx.x * 4 + (threadIdx.x >> 6);
    int lane = threadIdx.x & 63;
    float* base;
    int c;
    if (wid < 25600) { base = Pq; c = wid; }
    else             { base = Pk; c = wid - 25600; }
    float x = base[(size_t)c * 64 + lane];
    float ss = x * x;
#pragma unroll
    for (int m = 32; m >= 1; m >>= 1) ss += __shfl_xor(ss, m);
    float inv = 1.0f / fmaxf(sqrtf(ss), 1e-12f);
    base[(size_t)c * 64 + lane] = x * inv;
}

// ---------------------------------------------------------------------------
// Fused attention: one block handles one (bq, bk, h, half) task over 52/48
// query rows. S = relu(Qn@Kn^T)*20 -> softmax -> O = P@V.
// LDS: Sq 52x68 f32 (14.1KB) + Sk 100x68 (27.2KB, reused for V) +
//      Ss 52x104 (21.6KB) = 62976 B  -> 2 blocks/CU.
// ---------------------------------------------------------------------------
__global__ __launch_bounds__(256) void attn_fused(const float* __restrict__ Pq,
                                                  const float* __restrict__ Pk,
                                                  const float* __restrict__ V,
                                                  float* __restrict__ out) {
    __shared__ float Sq[52 * 68];
    __shared__ float Sk[100 * 68];   // K, later overwritten with V
    __shared__ float Ss[52 * 104];   // scores -> probs

    const int b    = blockIdx.x;
    const int h    = b & 7;
    const int bk   = (b >> 3) & 31;
    const int bq   = (b >> 8) & 31;
    const int half = b >> 13;                 // 0 or 1
    const int l0     = half * 52;
    const int lcount = half ? 48 : 52;

    const float* Qh = Pq + (size_t)bq * 51200 + h * 6400 + (size_t)l0 * 64;
    const float* Kh = Pk + (size_t)bk * 51200 + h * 6400;
    const float* Vh = V  + (size_t)bk * 51200 + h * 6400;

    const int t  = threadIdx.x;
    const int tx = t & 15, ty = t >> 4;

    // ---- stage Q (lcount rows x 64 cols, float4 granularity) ----
#pragma unroll
    for (int it = 0; it < 4; ++it) {
        int f = t + 256 * it;
        if (f < 52 * 16) {
            int row = f >> 4, c4 = (f & 15) << 2;
            if (row < lcount)
                *(float4*)&Sq[row * 68 + c4] = *(const float4*)&Qh[row * 64 + c4];
        }
    }
    // ---- stage K (100 rows) ----
#pragma unroll
    for (int it = 0; it < 7; ++it) {
        int f = t + 256 * it;
        if (f < 100 * 16) {
            int row = f >> 4, c4 = (f & 15) << 2;
            *(float4*)&Sk[row * 68 + c4] = *(const float4*)&Kh[row * 64 + c4];
        }
    }
    __syncthreads();

    // ---- phase 1: S = Qn @ Kn^T over this block's rows ----
    int lrow[4], mcol[7];
#pragma unroll
    for (int i = 0; i < 4; ++i) lrow[i] = min(ty + 16 * i, lcount - 1);
#pragma unroll
    for (int j = 0; j < 7; ++j) mcol[j] = min(tx + 16 * j, 99);

    float acc[4][7];
#pragma unroll
    for (int i = 0; i < 4; ++i)
#pragma unroll
        for (int j = 0; j < 7; ++j) acc[i][j] = 0.f;

#pragma unroll 4
    for (int d = 0; d < 64; d += 4) {
        float4 qv[4], kv[7];
#pragma unroll
        for (int i = 0; i < 4; ++i) qv[i] = *(const float4*)&Sq[lrow[i] * 68 + d];
#pragma unroll
        for (int j = 0; j < 7; ++j) kv[j] = *(const float4*)&Sk[mcol[j] * 68 + d];
#pragma unroll
        for (int i = 0; i < 4; ++i)
#pragma unroll
            for (int j = 0; j < 7; ++j)
                acc[i][j] += qv[i].x * kv[j].x + qv[i].y * kv[j].y +
                             qv[i].z * kv[j].z + qv[i].w * kv[j].w;
    }
#pragma unroll
    for (int i = 0; i < 4; ++i) {
        int li = ty + 16 * i;
#pragma unroll
        for (int j = 0; j < 7; ++j) {
            int mj = tx + 16 * j;
            if (li < lcount && mj < 100)
                Ss[li * 104 + mj] = fmaxf(acc[i][j], 0.f) * TEMP;
        }
    }
    __syncthreads();

    // ---- phase 2: row softmax (one wave per row, strided) ----
    {
        int wv = t >> 6, lane = t & 63;
        for (int r = wv; r < lcount; r += 4) {
            float s1 = Ss[r * 104 + lane];
            bool  v2 = lane < 36;
            float s2 = v2 ? Ss[r * 104 + 64 + lane] : -1e30f;
            float mx = fmaxf(s1, s2);
#pragma unroll
            for (int m = 32; m >= 1; m >>= 1) mx = fmaxf(mx, __shfl_xor(mx, m));
            float e1 = __expf(s1 - mx);
            float e2 = v2 ? __expf(s2 - mx) : 0.f;
            float sum = e1 + e2;
#pragma unroll
            for (int m = 32; m >= 1; m >>= 1) sum += __shfl_xor(sum, m);
            float inv = 1.0f / sum;
            Ss[r * 104 + lane] = e1 * inv;
            if (v2) Ss[r * 104 + 64 + lane] = e2 * inv;
        }
    }
    __syncthreads();

    // ---- stage V over the K buffer ----
#pragma unroll
    for (int it = 0; it < 7; ++it) {
        int f = t + 256 * it;
        if (f < 100 * 16) {
            int row = f >> 4, c4 = (f & 15) << 2;
            *(float4*)&Sk[row * 68 + c4] = *(const float4*)&Vh[row * 64 + c4];
        }
    }
    __syncthreads();

    // ---- phase 3: O = P @ V ; thread owns rows lrow[i], cols 4*tx..4*tx+3 ----
    float4 o[4];
#pragma unroll
    for (int i = 0; i < 4; ++i) o[i] = make_float4(0.f, 0.f, 0.f, 0.f);

    for (int m = 0; m < 100; ++m) {
        float4 vv = *(const float4*)&Sk[m * 68 + 4 * tx];
#pragma unroll
        for (int i = 0; i < 4; ++i) {
            float p = Ss[lrow[i] * 104 + m];
            o[i].x += p * vv.x; o[i].y += p * vv.y;
            o[i].z += p * vv.z; o[i].w += p * vv.w;
        }
    }

    const size_t obase = ((size_t)(bk * 32 + bq) * 100) * 512 + h * 64 + 4 * tx;
#pragma unroll
    for (int i = 0; i < 4; ++i) {
        int li = ty + 16 * i;
        if (li < lcount)
            *(float4*)&out[obase + (size_t)(l0 + li) * 512] = o[i];
    }
}

// ---------------------------------------------------------------------------
extern "C" void kernel_launch(void* const* d_in, const int* in_sizes, int n_in,
                              void* d_out, int out_size, void* d_ws, size_t ws_size,
                              hipStream_t stream) {
    const float* q  = (const float*)d_in[0];   // 32*100*512
    const float* k  = (const float*)d_in[1];   // 32*100*512
    const float* v  = (const float*)d_in[2];   // 32*100*512
    const float* wq = (const float*)d_in[3];   // 512*512
    const float* wk = (const float*)d_in[4];   // 512*512
    float* out = (float*)d_out;                // 32*32*100*512

    float* Pq = (float*)d_ws;                  // 3200*512 f32
    float* Pk = Pq + (size_t)3200 * 512;

    // Projections: M=3200, N=512 -> grid (50, 8)
    proj_gemm<<<dim3(50, 8), 256, 0, stream>>>(q, wq, Pq);
    proj_gemm<<<dim3(50, 8), 256, 0, stream>>>(k, wk, Pk);

    // Normalize all 64-chunks of both projections in place
    l2norm_chunks<<<12800, 256, 0, stream>>>(Pq, Pk);

    // Fused attention: 2 * 32 * 32 * 8 = 16384 blocks
    attn_fused<<<16384, 256, 0, stream>>>(Pq, Pk, v, out);
}

// Round 2
// 421.993 us; speedup vs baseline: 3.5085x; 3.5085x over previous
//
#include <hip/hip_runtime.h>
#include <math.h>

typedef short bf16x8 __attribute__((ext_vector_type(8)));  // 8 bf16 = 4 VGPRs
typedef float f32x4  __attribute__((ext_vector_type(4)));

#define TEMP 20.0f

__device__ __forceinline__ ushort f2bf(float f) {
    unsigned u = __float_as_uint(f);
    u = (u + 0x7FFFu + ((u >> 16) & 1u)) >> 16;   // RNE
    return (ushort)u;
}

__device__ __forceinline__ bf16x8 cvt8(const float4* p) {
    float4 a = p[0], b = p[1];
    bf16x8 r;
    r[0] = (short)f2bf(a.x); r[1] = (short)f2bf(a.y);
    r[2] = (short)f2bf(a.z); r[3] = (short)f2bf(a.w);
    r[4] = (short)f2bf(b.x); r[5] = (short)f2bf(b.y);
    r[6] = (short)f2bf(b.z); r[7] = (short)f2bf(b.w);
    return r;
}

// ---------------------------------------------------------------------------
// Fused projection + per-64-chunk L2 norm + bf16 store.
// C[3200,512] = A[3200,512] @ W[512,512]^T. Wave: 1 M-tile(16) x 64-col chunk.
// grid (200, 2), block 256 (4 waves): chunk = blockIdx.y*4 + wave.
// ---------------------------------------------------------------------------
__global__ __launch_bounds__(256) void proj_norm(const float* __restrict__ A,
                                                 const float* __restrict__ W,
                                                 ushort* __restrict__ Out) {
    const int lane = threadIdx.x & 63, w = threadIdx.x >> 6;
    const int l15 = lane & 15, quad = lane >> 4;
    const int mtile = blockIdx.x;
    const int chunk = blockIdx.y * 4 + w;
    const int m = mtile * 16 + l15;

    f32x4 acc[4];
#pragma unroll
    for (int nt = 0; nt < 4; ++nt) acc[nt] = (f32x4)(0.f);

    const float* arow = A + (size_t)m * 512 + quad * 8;
#pragma unroll 2
    for (int k0 = 0; k0 < 512; k0 += 32) {
        bf16x8 af = cvt8((const float4*)(arow + k0));
#pragma unroll
        for (int nt = 0; nt < 4; ++nt) {
            int n = chunk * 64 + nt * 16 + l15;
            bf16x8 bf = cvt8((const float4*)(W + (size_t)n * 512 + k0 + quad * 8));
            acc[nt] = __builtin_amdgcn_mfma_f32_16x16x32_bf16(af, bf, acc[nt], 0, 0, 0);
        }
    }
    // C/D layout: col = l15 (+16*nt), row = quad*4 + reg. Norm over the 64 cols.
#pragma unroll
    for (int reg = 0; reg < 4; ++reg) {
        float ss = 0.f;
#pragma unroll
        for (int nt = 0; nt < 4; ++nt) ss += acc[nt][reg] * acc[nt][reg];
#pragma unroll
        for (int o = 8; o >= 1; o >>= 1) ss += __shfl_xor(ss, o);
        float inv = 1.0f / fmaxf(sqrtf(ss), 1e-12f);
        int row = mtile * 16 + quad * 4 + reg;
#pragma unroll
        for (int nt = 0; nt < 4; ++nt)
            Out[(size_t)row * 512 + chunk * 64 + nt * 16 + l15] =
                f2bf(acc[nt][reg] * inv);
    }
}

// ---------------------------------------------------------------------------
// Vt[bk][h][n=0..63][k=0..127] bf16 = v[bk][flat h*6400 + k*64 + n], zero-pad k>=100.
// One block per (bk,h).
// ---------------------------------------------------------------------------
__global__ __launch_bounds__(256) void vt_build(const float* __restrict__ V,
                                                ushort* __restrict__ Vt) {
    __shared__ float T[100 * 65];
    const int b = blockIdx.x;              // bk*8 + h
    const int t = threadIdx.x;
    const float* in = V + (size_t)(b >> 3) * 51200 + (b & 7) * 6400;
    for (int i = t; i < 6400; i += 256) T[(i >> 6) * 65 + (i & 63)] = in[i];
    __syncthreads();
    const int n = t >> 2, kc = (t & 3) * 32;
    unsigned* outw = (unsigned*)(Vt + (((size_t)b * 64 + n) * 128 + kc));
#pragma unroll
    for (int i = 0; i < 16; ++i) {
        int l0 = kc + 2 * i, l1 = l0 + 1;
        unsigned lo = (l0 < 100) ? (unsigned)f2bf(T[l0 * 65 + n]) : 0u;
        unsigned hi = (l1 < 100) ? (unsigned)f2bf(T[l1 * 65 + n]) : 0u;
        outw[i] = lo | (hi << 16);
    }
}

// ---------------------------------------------------------------------------
// Fused attention, full MFMA. One block per (bq,bk,h); wave w owns M-tiles
// {w, w+4<7}. S=relu(Qn Kn^T)*20 -> in-register softmax -> P bf16 via LDS ->
// O = P V via MFMA. Q/K/V fragments loaded directly from global (L2-resident).
// ---------------------------------------------------------------------------
__global__ __launch_bounds__(256) void attn_mfma(const ushort* __restrict__ Pqn,
                                                 const ushort* __restrict__ Pkn,
                                                 const ushort* __restrict__ Vt,
                                                 float* __restrict__ out) {
    __shared__ short Ps[112 * 136];        // P, stride 136 bf16 (68 dw ≡ 4 mod 32)

    const int blk = blockIdx.x;
    const int h = blk & 7, bk = (blk >> 3) & 31, bq = blk >> 8;
    const int lane = threadIdx.x & 63, w = threadIdx.x >> 6;
    const int l15 = lane & 15, quad = lane >> 4;

    const ushort* Qb = Pqn + (size_t)bq * 51200 + h * 6400;
    const ushort* Kb = Pkn + (size_t)bk * 51200 + h * 6400;
    const ushort* Vb = Vt + (size_t)(bk * 8 + h) * 64 * 128;

    const int nmt = (w + 4 < 7) ? 2 : 1;   // wave 3 owns only tile 3

    // ---- S = Qn @ Kn^T : M-tiles {w, w+4}, 7 N-tiles, K=64 (2 k-steps) ----
    f32x4 sacc[2][7];
#pragma unroll
    for (int mt = 0; mt < 2; ++mt)
#pragma unroll
        for (int nt = 0; nt < 7; ++nt) sacc[mt][nt] = (f32x4)(0.f);

    bf16x8 aq[2][2];
#pragma unroll
    for (int mt = 0; mt < 2; ++mt)
        if (mt < nmt)
#pragma unroll
            for (int ki = 0; ki < 2; ++ki)
                aq[mt][ki] = *(const bf16x8*)(Qb + ((w + 4 * mt) * 16 + l15) * 64 +
                                              ki * 32 + quad * 8);
#pragma unroll
    for (int nt = 0; nt < 7; ++nt) {
#pragma unroll
        for (int ki = 0; ki < 2; ++ki) {
            bf16x8 bkf = *(const bf16x8*)(Kb + (nt * 16 + l15) * 64 + ki * 32 + quad * 8);
            sacc[0][nt] = __builtin_amdgcn_mfma_f32_16x16x32_bf16(aq[0][ki], bkf, sacc[0][nt], 0, 0, 0);
            if (nmt == 2)
                sacc[1][nt] = __builtin_amdgcn_mfma_f32_16x16x32_bf16(aq[1][ki], bkf, sacc[1][nt], 0, 0, 0);
        }
    }

    // ---- softmax in-register; write P (bf16) to LDS in row-major ----
#pragma unroll
    for (int mt = 0; mt < 2; ++mt) {
        if (mt >= nmt) break;
        const int tile = w + 4 * mt;
#pragma unroll
        for (int reg = 0; reg < 4; ++reg) {
            float mx = -1e30f;
#pragma unroll
            for (int nt = 0; nt < 7; ++nt) {
                float v2 = fmaxf(sacc[mt][nt][reg], 0.f) * TEMP;
                if (nt == 6 && l15 >= 4) v2 = -1e30f;   // cols >= 100 masked
                sacc[mt][nt][reg] = v2;
                mx = fmaxf(mx, v2);
            }
#pragma unroll
            for (int o = 8; o >= 1; o >>= 1) mx = fmaxf(mx, __shfl_xor(mx, o));
            float sum = 0.f;
#pragma unroll
            for (int nt = 0; nt < 7; ++nt) {
                float e = __expf(sacc[mt][nt][reg] - mx);
                sacc[mt][nt][reg] = e;
                sum += e;
            }
#pragma unroll
            for (int o = 8; o >= 1; o >>= 1) sum += __shfl_xor(sum, o);
            float inv = 1.0f / sum;
            int row = tile * 16 + quad * 4 + reg;
#pragma unroll
            for (int nt = 0; nt < 7; ++nt)
                Ps[row * 136 + nt * 16 + l15] = (short)f2bf(sacc[mt][nt][reg] * inv);
        }
        // zero cols 112..127 of this tile's 16 rows (8 dwords per row)
        int* pz = (int*)Ps;
        pz[(tile * 16 + (lane >> 3)) * 68 + 56 + (lane & 7)] = 0;
        pz[(tile * 16 + 8 + (lane >> 3)) * 68 + 56 + (lane & 7)] = 0;
    }
    __syncthreads();

    // ---- O = P @ V : K = 128 (zero-padded), N = 64 (4 tiles) ----
    f32x4 oacc[2][4];
#pragma unroll
    for (int mt = 0; mt < 2; ++mt)
#pragma unroll
        for (int nt = 0; nt < 4; ++nt) oacc[mt][nt] = (f32x4)(0.f);

#pragma unroll
    for (int ki = 0; ki < 4; ++ki) {
        bf16x8 ap[2];
#pragma unroll
        for (int mt = 0; mt < 2; ++mt)
            if (mt < nmt)
                ap[mt] = *(const bf16x8*)&Ps[((w + 4 * mt) * 16 + l15) * 136 +
                                             ki * 32 + quad * 8];
#pragma unroll
        for (int nt = 0; nt < 4; ++nt) {
            bf16x8 bv = *(const bf16x8*)(Vb + (nt * 16 + l15) * 128 + ki * 32 + quad * 8);
            oacc[0][nt] = __builtin_amdgcn_mfma_f32_16x16x32_bf16(ap[0], bv, oacc[0][nt], 0, 0, 0);
            if (nmt == 2)
                oacc[1][nt] = __builtin_amdgcn_mfma_f32_16x16x32_bf16(ap[1], bv, oacc[1][nt], 0, 0, 0);
        }
    }

    const size_t ob = ((size_t)(bk * 32 + bq) * 100) * 512 + h * 64;
#pragma unroll
    for (int mt = 0; mt < 2; ++mt) {
        if (mt >= nmt) break;
#pragma unroll
        for (int reg = 0; reg < 4; ++reg) {
            int r = (w + 4 * mt) * 16 + quad * 4 + reg;
            if (r < 100) {
#pragma unroll
                for (int nt = 0; nt < 4; ++nt)
                    out[ob + (size_t)r * 512 + nt * 16 + l15] = oacc[mt][nt][reg];
            }
        }
    }
}

// ---------------------------------------------------------------------------
extern "C" void kernel_launch(void* const* d_in, const int* in_sizes, int n_in,
                              void* d_out, int out_size, void* d_ws, size_t ws_size,
                              hipStream_t stream) {
    const float* q  = (const float*)d_in[0];
    const float* k  = (const float*)d_in[1];
    const float* v  = (const float*)d_in[2];
    const float* wq = (const float*)d_in[3];
    const float* wk = (const float*)d_in[4];
    float* out = (float*)d_out;

    // ws: Pqn | Pkn | Vt  (bf16), with slack for padded-row overreads
    ushort* Pqn = (ushort*)d_ws;                       // 32*51200 (+slack)
    ushort* Pkn = Pqn + 1703936;
    ushort* Vt  = Pkn + 1703936;                       // 32*8*64*128

    proj_norm<<<dim3(200, 2), 256, 0, stream>>>(q, wq, Pqn);
    proj_norm<<<dim3(200, 2), 256, 0, stream>>>(k, wk, Pkn);
    vt_build<<<256, 256, 0, stream>>>(v, Vt);
    attn_mfma<<<8192, 256, 0, stream>>>(Pqn, Pkn, Vt, out);
}